// Round 9
// baseline (891.971 us; speedup 1.0000x reference)
//
#include <hip/hip_runtime.h>
#include <cstdint>
#include <cstddef>

typedef unsigned short u16;
typedef unsigned int   u32;
typedef __attribute__((ext_vector_type(8))) short bf16x8;
typedef __attribute__((ext_vector_type(4))) float f32x4;

#define NB   16
#define LL   1024
#define CIN  300
#define CINP 320              /* padded channels: rows 640B, 16B aligned */
#define XPBP (LL*CINP)        /* 327680 elems per batch */
#define XELP (NB*XPBP)        /* 5242880 */
#define NCH  6000
#define NCHP 6144             /* padded to 24*256 */
#define ODIM 100
#define OUTN (NB*ODIM*180)    /* 288000 */
#define TOTSTEPS 270          /* exactly 270 K-steps per CU */

#define BM 256
#define BN 256
#define BK 64

__device__ __forceinline__ u16 f2bf(float f) {
  union { float f; u32 u; } v; v.f = f;
  return (u16)((v.u + 0x7FFFu + ((v.u >> 16) & 1u)) >> 16);   // RNE, inputs finite
}

typedef __attribute__((address_space(1))) const unsigned int gu32;
typedef __attribute__((address_space(3))) unsigned int lu32;
__device__ __forceinline__ void gload_lds16(const void* g, void* l) {
  __builtin_amdgcn_global_load_lds((gu32*)g, (lu32*)l, 16, 0, 0);
}

#define BAR() asm volatile("s_barrier" ::: "memory")
#define VM2  asm volatile("s_waitcnt vmcnt(2)" ::: "memory")
#define VM0  asm volatile("s_waitcnt vmcnt(0)" ::: "memory")

// ---- merged prep: zero out (141) + repack W (3*NCHP) + cvt x (2560) ------
__global__ void prep_kernel(const float* __restrict__ x,
                            const float* __restrict__ W2, const float* __restrict__ W3,
                            const float* __restrict__ W4,
                            u16* __restrict__ xb, u16* __restrict__ wb,
                            float* __restrict__ out) {
  int bid = blockIdx.x;
  if (bid < 141) {
    // zero d_out (atomicMax identity; all results are relu >= 0)
    int i8 = (bid * 256 + threadIdx.x) * 8;
    if (i8 < OUTN) {           // OUTN % 8 == 0
      *(float4*)(out + i8)     = make_float4(0.f, 0.f, 0.f, 0.f);
      *(float4*)(out + i8 + 4) = make_float4(0.f, 0.f, 0.f, 0.f);
    }
  } else if (bid < 141 + 3 * NCHP) {
    // W[n,o,c,j] f32 -> Wb[no][kp = j*320 + c] bf16 (zeros c>=300, no>=6000)
    int wbid = bid - 141;
    int g  = wbid / NCHP;
    int no = wbid - g * NCHP;                  // 0..6143
    int kk = g + 2;
    int Kp = kk * CINP;
    int woff = (g == 0) ? 0 : (g == 1) ? NCHP*640 : NCHP*(640+960);
    const float* W = (g == 0) ? W2 : (g == 1) ? W3 : W4;
    u16* dst = wb + (size_t)woff + (size_t)no * Kp;
    const float* src = W + (size_t)no * (CIN * kk);
    for (int kp = threadIdx.x; kp < Kp; kp += 256) {
      int j = kp / CINP, c = kp - j * CINP;
      u16 v = 0;
      if (no < NCH && c < CIN) v = f2bf(src[c * kk + j]);
      dst[kp] = v;
    }
  } else {
    // x [16,1024,300] f32 -> xb [16,1024,320] bf16 (zero-pad channels)
    int i8 = ((bid - 141 - 3 * NCHP) * 256 + threadIdx.x) * 8;   // 2560 blocks
    int row = i8 / CINP;
    int col = i8 - row * CINP;
    const float* src = x + (size_t)row * CIN + col;
    u16 e[8];
    if (col + 8 <= CIN) {
      float4 a = *(const float4*)src;
      float4 b = *(const float4*)(src + 4);
      e[0]=f2bf(a.x); e[1]=f2bf(a.y); e[2]=f2bf(a.z); e[3]=f2bf(a.w);
      e[4]=f2bf(b.x); e[5]=f2bf(b.y); e[6]=f2bf(b.z); e[7]=f2bf(b.w);
    } else {
      #pragma unroll
      for (int j = 0; j < 8; j++)
        e[j] = (col + j < CIN) ? f2bf(src[j]) : (u16)0;
    }
    uint4 o;
    o.x = (u32)e[0] | ((u32)e[1] << 16);
    o.y = (u32)e[2] | ((u32)e[3] << 16);
    o.z = (u32)e[4] | ((u32)e[5] << 16);
    o.w = (u32)e[6] | ((u32)e[7] << 16);
    *(uint4*)(xb + i8) = o;
  }
}

// ---- persistent fused GEMM + running-max + bias + relu -------------------
// 256 blocks (1/CU), each runs EXACTLY 270 K-steps through ONE continuous
// 8-phase tail-read pipeline (r7 schedule, verified): 9 segments =
// 3x(g=2,40 steps) + 3x(g=1,30) + 3x(g=0,20). Segment = 2 t-tiles of a
// (g,b,chblk) unit; partial results combine via atomicMax (relu>=0,
// out zero-initialized; max commutes with monotone relu+bias).
// Flush uses raw barriers + lgkmcnt only — NEVER vmcnt(0) — so the
// staging pipeline stays in flight across segment boundaries.
__global__ __launch_bounds__(512, 1)
void gemm_max_kernel(const u16* __restrict__ xb, const u16* __restrict__ wb,
                     const float* __restrict__ b2v, const float* __restrict__ b3v,
                     const float* __restrict__ b4v, float* __restrict__ out) {
  const int cu = blockIdx.x;       // 0..255

  __shared__ __align__(16) u16 smem[4 * 16384];     // 128 KiB staging
  __shared__ float scratch[512];                    // 2 KiB flush scratch
  u16* A0s = smem;
  u16* B0s = smem + 16384;
  u16* A1s = smem + 32768;
  u16* B1s = smem + 49152;

  const int tid  = threadIdx.x;
  const int lane = tid & 63;
  const int w    = tid >> 6;       // 0..7
  const int wr   = w >> 2;         // 0..1 : M interleave
  const int wc   = w & 3;          // 0..3 : N interleave

  // segment decode: seg 0..8 -> (g, b, chblk, tpair)
  auto segdec = [&](int seg, int& g, int& bb, int& cb, int& tp) {
    g = (seg < 3) ? 2 : (seg < 6) ? 1 : 0;
    int hu = cu * 3 + (seg - (2 - g) * 3);   // 0..767
    bb = hu / 48; int r = hu - bb * 48; cb = r >> 1; tp = r & 1;
  };

  // staging cursor (leads compute by one step)
  int sc_seg = 0, sc_tile = 0, sc_ks = 0;
  auto stgaddr = [&](const u16*& sA, const u16*& sB, int& sKp) {
    int g, bb, cb, tp; segdec(sc_seg, g, bb, cb, tp);
    int Kp = (g + 2) * CINP;
    int woff = (g == 0) ? 0 : (g == 1) ? NCHP*640 : NCHP*(640+960);
    sA = xb + (size_t)bb * XPBP + (size_t)(tp * 2 + sc_tile) * (256 * CINP) + sc_ks * 64;
    sB = wb + (size_t)woff + (size_t)cb * BN * Kp + sc_ks * 64;
    sKp = Kp;
  };
  auto adv = [&]() {
    int g = (sc_seg < 3) ? 2 : (sc_seg < 6) ? 1 : 0;
    int nks = (g + 2) * 5;         // 10 / 15 / 20
    if (++sc_ks == nks) { sc_ks = 0; if (++sc_tile == 2) { sc_tile = 0; ++sc_seg; } }
  };

  // stage one 128x64 half: linear LDS dest, inverse-swizzled global src
  auto STAGE = [&](const u16* src, int stride, u16* buf, int half) {
    #pragma unroll
    for (int i = 0; i < 2; i++) {
      int c = i * 512 + w * 64 + lane;                  // chunk 0..1023
      int row128 = c >> 3;
      int colb = ((c & 7) * 16) ^ ((row128 & 7) << 4);  // involution
      gload_lds16(src + (size_t)(half * 128 + row128) * stride + (colb >> 1),
                  buf + half * 8192 + i * 4096 + w * 512);
    }
  };

  // swizzled fragment read (16x16x32, verified r3..r7)
  auto FR = [&](const u16* buf, int grp, int k) -> bf16x8 {
    int row  = grp * 16 + (lane & 15);
    int colb = (k * 64 + ((lane >> 4) << 4)) ^ ((lane & 7) << 4);
    return *(const bf16x8*)(buf + row * 64 + (colb >> 1));
  };

  f32x4 acc[8][4];
  #pragma unroll
  for (int mi = 0; mi < 8; mi++)
    #pragma unroll
    for (int ni = 0; ni < 4; ni++)
      acc[mi][ni] = (f32x4){0.f, 0.f, 0.f, 0.f};

  bf16x8 afrA[4][2];      // A-half-0 frags (ph1, ph2)
  bf16x8 afrB[4][2];      // A-half-1 frags (ph3, ph4)
  bf16x8 bfr[2][2][2];    // [nh][b2][k2]
  float rmax[4] = { -1e30f, -1e30f, -1e30f, -1e30f };

#define READ_A(DST, BUF, MH) do {                                             \
    _Pragma("unroll")                                                         \
    for (int a2 = 0; a2 < 4; a2++) {                                          \
      _Pragma("unroll")                                                       \
      for (int k2 = 0; k2 < 2; k2++)                                          \
        DST[a2][k2] = FR(BUF, ((MH)*4 + a2) * 2 + wr, k2);                    \
    }                                                                         \
  } while (0)

#define READ_B(NH, BUF) do {                                                  \
    _Pragma("unroll")                                                         \
    for (int b2 = 0; b2 < 2; b2++) {                                          \
      _Pragma("unroll")                                                       \
      for (int k2 = 0; k2 < 2; k2++)                                          \
        bfr[NH][b2][k2] = FR(BUF, ((NH)*2 + b2) * 4 + wc, k2);                \
    }                                                                         \
  } while (0)

#define MFMAQ(MH, NH, A) do {                                                 \
    __builtin_amdgcn_s_setprio(1);                                            \
    _Pragma("unroll")                                                         \
    for (int a2 = 0; a2 < 4; a2++)                                            \
      _Pragma("unroll")                                                       \
      for (int b2 = 0; b2 < 2; b2++)                                          \
        _Pragma("unroll")                                                     \
        for (int k2 = 0; k2 < 2; k2++)                                        \
          acc[(MH)*4 + a2][(NH)*2 + b2] =                                     \
            __builtin_amdgcn_mfma_f32_16x16x32_bf16(A[a2][k2],                \
              bfr[NH][b2][k2], acc[(MH)*4 + a2][(NH)*2 + b2], 0, 0, 0);       \
    __builtin_amdgcn_s_setprio(0);                                            \
  } while (0)

  // ---- prologue: stage step 0 -> buf0, order [A-h0, B-h0, B-h1, A-h1] ----
  {
    const u16 *sA, *sB; int sKp;
    stgaddr(sA, sB, sKp);         // cursor at step 0
    STAGE(sA, CINP, A0s, 0);
    STAGE(sB, sKp, B0s, 0);
    STAGE(sB, sKp, B0s, 1);
    STAGE(sA, CINP, A0s, 1);
    adv();                        // cursor -> step 1
  }
  VM2;                            // A-h0, B-h0, B-h1 certified
  BAR();
  READ_A(afrA, A0s, 0);
  READ_B(0, B0s);

  int step = 0;
  for (int seg = 0; seg < 9; seg++) {
    int g, bb, cb, tp; segdec(seg, g, bb, cb, tp);
    const int nks = (g + 2) * 5;
    const int Lt  = LL - (g + 2) + 1;

    for (int tile = 0; tile < 2; tile++) {
      for (int ks = 0; ks < nks; ks++, step++) {
        u16* cA = (step & 1) ? A1s : A0s;
        u16* cB = (step & 1) ? B1s : B0s;
        u16* nA = (step & 1) ? A0s : A1s;
        u16* nB = (step & 1) ? B0s : B1s;

        if (step < TOTSTEPS - 1) {
          const u16 *sA, *sB; int sKp;
          stgaddr(sA, sB, sKp);   // addresses for step+1
          adv();
          // ph1
          STAGE(sA, CINP, nA, 0);
          BAR();
          MFMAQ(0, 0, afrA);
          VM2;                     // certify cur A-h1
          READ_B(1, cB);           // cur B-h1 (certified prev ph4-end)
          BAR();
          // ph2
          STAGE(sB, sKp, nB, 0);
          BAR();
          MFMAQ(0, 1, afrA);
          READ_A(afrB, cA, 1);     // cur A-h1 (certified ph1-end)
          BAR();
          // ph3
          STAGE(sB, sKp, nB, 1);
          BAR();
          MFMAQ(1, 0, afrB);
          VM2;                     // certify nA-h0, nB-h0
          BAR();
          // ph4
          STAGE(sA, CINP, nA, 1);
          BAR();
          MFMAQ(1, 1, afrB);
          VM2;                     // certify nB-h1
          READ_A(afrA, nA, 0);     // next A-h0 (certified ph3-end)
          READ_B(0, nB);           // next B-h0 (certified ph3-end)
          BAR();
        } else {
          // ---- peeled final step (no staging; drain) ----
          MFMAQ(0, 0, afrA);
          VM0;
          READ_B(1, cB);
          BAR();
          MFMAQ(0, 1, afrA);
          READ_A(afrB, cA, 1);
          MFMAQ(1, 0, afrB);
          MFMAQ(1, 1, afrB);
        }
      }

      // fold this t-tile into running max (mask t >= Lt) and reset acc
      {
        int ttabs = tp * 2 + tile;
        #pragma unroll
        for (int mi = 0; mi < 8; mi++) {
          int tb = ttabs * 256 + (mi * 2 + wr) * 16 + ((lane >> 4) << 2);
          #pragma unroll
          for (int r = 0; r < 4; r++) {
            bool ok = (tb + r) < Lt;
            #pragma unroll
            for (int ni = 0; ni < 4; ni++)
              if (ok) rmax[ni] = fmaxf(rmax[ni], acc[mi][ni][r]);
          }
          #pragma unroll
          for (int ni = 0; ni < 4; ni++)
            acc[mi][ni] = (f32x4){0.f, 0.f, 0.f, 0.f};
        }
      }
    }

    // ---- segment flush: cross-lane + cross-wave max, bias+relu, atomicMax.
    // Raw barriers + lgkmcnt only: staging pipeline stays in flight.
    {
      float cv[4];
      #pragma unroll
      for (int ni = 0; ni < 4; ni++) {
        float v = rmax[ni];
        v = fmaxf(v, __shfl_xor(v, 16));
        v = fmaxf(v, __shfl_xor(v, 32));
        cv[ni] = v;
        rmax[ni] = -1e30f;
      }
      if (lane < 16) {
        #pragma unroll
        for (int ni = 0; ni < 4; ni++)
          scratch[wr * 256 + (ni * 4 + wc) * 16 + lane] = cv[ni];
      }
      asm volatile("s_waitcnt lgkmcnt(0)" ::: "memory");
      BAR();
      const float* bias = (g == 0) ? b2v : (g == 1) ? b3v : b4v;
      if (tid < 256) {
        float v = fmaxf(scratch[tid], scratch[256 + tid]);
        int ch = cb * BN + tid;
        if (ch < NCH) {
          int n = ch / ODIM, o = ch - n * ODIM;
          float r = fmaxf(v + bias[ch], 0.f);
          atomicMax((u32*)&out[bb * (ODIM * 180) + o * 180 + g * 60 + n],
                    __float_as_uint(r));
        }
      }
      asm volatile("s_waitcnt lgkmcnt(0)" ::: "memory");
      BAR();
    }
  }
#undef READ_A
#undef READ_B
#undef MFMAQ
}

extern "C" void kernel_launch(void* const* d_in, const int* in_sizes, int n_in,
                              void* d_out, int out_size, void* d_ws, size_t ws_size,
                              hipStream_t stream) {
  const float* x  = (const float*)d_in[0];
  const float* W2 = (const float*)d_in[1];
  const float* b2 = (const float*)d_in[2];
  const float* W3 = (const float*)d_in[3];
  const float* b3 = (const float*)d_in[4];
  const float* W4 = (const float*)d_in[5];
  const float* b4 = (const float*)d_in[6];
  float* out = (float*)d_out;

  u16* xb = (u16*)d_ws;            // XELP bf16 (10.5 MB)
  u16* wb = xb + XELP;             // NCHP*(640+960+1280) bf16 (35.4 MB)

  prep_kernel<<<141 + 3 * NCHP + XELP / (256 * 8), 256, 0, stream>>>(
      x, W2, W3, W4, xb, wb, out);
  gemm_max_kernel<<<dim3(256), 512, 0, stream>>>(xb, wb, b2, b3, b4, out);
}

// Round 10
// 531.364 us; speedup vs baseline: 1.6786x; 1.6786x over previous
//
#include <hip/hip_runtime.h>
#include <cstdint>
#include <cstddef>

typedef unsigned short u16;
typedef unsigned int   u32;
typedef __attribute__((ext_vector_type(8))) short bf16x8;
typedef __attribute__((ext_vector_type(4))) float f32x4;

#define NB   16
#define LL   1024
#define CIN  300
#define CINP 320              /* padded channels: rows 640B, 16B aligned */
#define XPBP (LL*CINP)        /* 327680 elems per batch */
#define XELP (NB*XPBP)        /* 5242880 */
#define NCH  6000
#define NCHP 6144             /* padded to 24*256 */
#define ODIM 100

#define BM 256
#define BN 256
#define BK 64

__device__ __forceinline__ u16 f2bf(float f) {
  union { float f; u32 u; } v; v.f = f;
  return (u16)((v.u + 0x7FFFu + ((v.u >> 16) & 1u)) >> 16);   // RNE, inputs finite
}

typedef __attribute__((address_space(1))) const unsigned int gu32;
typedef __attribute__((address_space(3))) unsigned int lu32;
__device__ __forceinline__ void gload_lds16(const void* g, void* l) {
  __builtin_amdgcn_global_load_lds((gu32*)g, (lu32*)l, 16, 0, 0);
}

#define BAR() asm volatile("s_barrier" ::: "memory")
#define VM2  asm volatile("s_waitcnt vmcnt(2)" ::: "memory")
#define VM0  asm volatile("s_waitcnt vmcnt(0)" ::: "memory")

// ---- merged prep: repack W (blocks 0..18431) + cvt x (blocks 18432..20991)
// Disjoint outputs (wb vs xb) -> safe to run concurrently in one grid.
__global__ void prep_kernel(const float* __restrict__ x,
                            const float* __restrict__ W2, const float* __restrict__ W3,
                            const float* __restrict__ W4,
                            u16* __restrict__ xb, u16* __restrict__ wb) {
  int bid = blockIdx.x;
  if (bid < 3 * NCHP) {
    // ---- W[n,o,c,j] f32 -> Wb[no][kp = j*320 + c] bf16 (zeros c>=300, no>=6000)
    int g  = bid / NCHP;
    int no = bid - g * NCHP;                   // 0..6143
    int kk = g + 2;
    int Kp = kk * CINP;
    int woff = (g == 0) ? 0 : (g == 1) ? NCHP*640 : NCHP*(640+960);
    const float* W = (g == 0) ? W2 : (g == 1) ? W3 : W4;
    u16* dst = wb + (size_t)woff + (size_t)no * Kp;
    const float* src = W + (size_t)no * (CIN * kk);
    for (int kp = threadIdx.x; kp < Kp; kp += 256) {
      int j = kp / CINP, c = kp - j * CINP;
      u16 v = 0;
      if (no < NCH && c < CIN) v = f2bf(src[c * kk + j]);
      dst[kp] = v;
    }
  } else {
    // ---- x [16,1024,300] f32 -> xb [16,1024,320] bf16 (zero-pad channels)
    int i8 = ((bid - 3 * NCHP) * 256 + threadIdx.x) * 8;   // 2560 blocks
    int row = i8 / CINP;
    int col = i8 - row * CINP;
    const float* src = x + (size_t)row * CIN + col;
    u16 e[8];
    if (col + 8 <= CIN) {
      float4 a = *(const float4*)src;
      float4 b = *(const float4*)(src + 4);
      e[0]=f2bf(a.x); e[1]=f2bf(a.y); e[2]=f2bf(a.z); e[3]=f2bf(a.w);
      e[4]=f2bf(b.x); e[5]=f2bf(b.y); e[6]=f2bf(b.z); e[7]=f2bf(b.w);
    } else {
      #pragma unroll
      for (int j = 0; j < 8; j++)
        e[j] = (col + j < CIN) ? f2bf(src[j]) : (u16)0;
    }
    uint4 o;
    o.x = (u32)e[0] | ((u32)e[1] << 16);
    o.y = (u32)e[2] | ((u32)e[3] << 16);
    o.z = (u32)e[4] | ((u32)e[5] << 16);
    o.w = (u32)e[6] | ((u32)e[7] << 16);
    *(uint4*)(xb + i8) = o;
  }
}

// ---- fused GEMM + running-max + bias + relu ------------------------------
// 256^2 8-phase (T2+T3+T4+T5) with TAIL-READ schedule (r7, verified):
// each phase's frags are ds_read at the END of the previous phase
// (post-vmcnt, pre-barrier), so MFMA operands are in-register when the
// leading barrier opens. Certification chain (all-waves vmcnt + barrier
// BEFORE any cross-wave read):
//   ph3-end vmcnt(2) -> {nA0,nB0} certified for ph4-tail reads
//   ph4-end vmcnt(2) -> {nB1}     certified for ph1-tail read
//   ph1-end vmcnt(2) -> {cur A1}  certified for ph2-tail read
// WAR on buffer reuse closed by compiler lgkm waits at each MFMA.
__global__ __launch_bounds__(512, 1)
void gemm_max_kernel(const u16* __restrict__ xb, const u16* __restrict__ wb,
                     const float* __restrict__ b2v, const float* __restrict__ b3v,
                     const float* __restrict__ b4v, float* __restrict__ out) {
  // LPT remap: ids 0..383 -> g=2, 384..767 -> g=1, 768..1151 -> g=0
  const int id    = blockIdx.x;
  const int g     = 2 - (id / 384);
  const int id2   = id % 384;
  const int b     = id2 / 24;      // 0..15
  const int chblk = id2 % 24;      // 0..23
  const int Kp    = (g + 2) * CINP;                 // 640 / 960 / 1280
  const int nks   = Kp >> 6;                        // 10 / 15 / 20
  const int woff  = (g == 0) ? 0 : (g == 1) ? NCHP*640 : NCHP*(640+960);
  const int Lt    = LL - (g + 2) + 1;

  __shared__ __align__(16) u16 smem[4 * 16384];     // 128 KiB
  u16* A0s = smem;
  u16* B0s = smem + 16384;
  u16* A1s = smem + 32768;
  u16* B1s = smem + 49152;

  const int tid  = threadIdx.x;
  const int lane = tid & 63;
  const int w    = tid >> 6;       // 0..7
  const int wr   = w >> 2;         // 0..1 : M interleave
  const int wc   = w & 3;          // 0..3 : N interleave

  const u16* __restrict__ xrow = xb + (size_t)b * XPBP;
  const u16* __restrict__ Wg   = wb + (size_t)woff + (size_t)chblk * BN * Kp;

  // stage one 128x64 half: linear LDS dest (wave-uniform base), inverse-swizzled src
  auto STAGE = [&](const u16* src, int stride, u16* buf, int half) {
    #pragma unroll
    for (int i = 0; i < 2; i++) {
      int c = i * 512 + w * 64 + lane;                  // chunk 0..1023
      int row128 = c >> 3;
      int colb = ((c & 7) * 16) ^ ((row128 & 7) << 4);  // inverse swizzle (involution)
      gload_lds16(src + (size_t)(half * 128 + row128) * stride + (colb >> 1),
                  buf + half * 8192 + i * 4096 + w * 512);
    }
  };

  // swizzled fragment read: group grp (16 rows), ksub k
  auto FR = [&](const u16* buf, int grp, int k) -> bf16x8 {
    int row  = grp * 16 + (lane & 15);
    int colb = (k * 64 + ((lane >> 4) << 4)) ^ ((lane & 7) << 4);  // row&7 == lane&7
    return *(const bf16x8*)(buf + row * 64 + (colb >> 1));
  };

  f32x4 acc[8][4];
  #pragma unroll
  for (int mi = 0; mi < 8; mi++)
    #pragma unroll
    for (int ni = 0; ni < 4; ni++)
      acc[mi][ni] = (f32x4){0.f, 0.f, 0.f, 0.f};

  bf16x8 afrA[4][2];      // A-half-0 frags (used ph1, ph2)
  bf16x8 afrB[4][2];      // A-half-1 frags (used ph3, ph4)
  bf16x8 bfr[2][2][2];    // [nh][b2][k2]
  float rmax[4] = { -1e30f, -1e30f, -1e30f, -1e30f };

  auto FOLD = [&](int ttf) {
    #pragma unroll
    for (int mi = 0; mi < 8; mi++) {
      int tb = ttf * 256 + (mi * 2 + wr) * 16 + ((lane >> 4) << 2);
      #pragma unroll
      for (int r = 0; r < 4; r++) {
        bool ok = (tb + r) < Lt;
        #pragma unroll
        for (int ni = 0; ni < 4; ni++)
          if (ok) rmax[ni] = fmaxf(rmax[ni], acc[mi][ni][r]);
      }
      #pragma unroll
      for (int ni = 0; ni < 4; ni++)
        acc[mi][ni] = (f32x4){0.f, 0.f, 0.f, 0.f};
    }
  };

#define READ_A(DST, BUF, MH) do {                                             \
    _Pragma("unroll")                                                         \
    for (int a2 = 0; a2 < 4; a2++) {                                          \
      _Pragma("unroll")                                                       \
      for (int k2 = 0; k2 < 2; k2++)                                          \
        DST[a2][k2] = FR(BUF, ((MH)*4 + a2) * 2 + wr, k2);                    \
    }                                                                         \
  } while (0)

#define READ_B(NH, BUF) do {                                                  \
    _Pragma("unroll")                                                         \
    for (int b2 = 0; b2 < 2; b2++) {                                          \
      _Pragma("unroll")                                                       \
      for (int k2 = 0; k2 < 2; k2++)                                          \
        bfr[NH][b2][k2] = FR(BUF, ((NH)*2 + b2) * 4 + wc, k2);                \
    }                                                                         \
  } while (0)

#define MFMAQ(MH, NH, A) do {                                                 \
    __builtin_amdgcn_s_setprio(1);                                            \
    _Pragma("unroll")                                                         \
    for (int a2 = 0; a2 < 4; a2++)                                            \
      _Pragma("unroll")                                                       \
      for (int b2 = 0; b2 < 2; b2++)                                          \
        _Pragma("unroll")                                                     \
        for (int k2 = 0; k2 < 2; k2++)                                        \
          acc[(MH)*4 + a2][(NH)*2 + b2] =                                     \
            __builtin_amdgcn_mfma_f32_16x16x32_bf16(A[a2][k2],                \
              bfr[NH][b2][k2], acc[(MH)*4 + a2][(NH)*2 + b2], 0, 0, 0);       \
    __builtin_amdgcn_s_setprio(0);                                            \
  } while (0)

  const int NT = 4 * nks;    // 40 / 60 / 80 (always even)
  int tt = 0, ks = 0;

  // ---- prologue: tile0 -> buf0, order [A-h0, B-h0, B-h1, A-h1] ----
  STAGE(xrow, CINP, A0s, 0);
  STAGE(Wg,   Kp,   B0s, 0);
  STAGE(Wg,   Kp,   B0s, 1);
  STAGE(xrow, CINP, A0s, 1);
  VM2;                       // A-h0, B-h0, B-h1 certified (A-h1 outstanding)
  BAR();
  READ_A(afrA, A0s, 0);
  READ_B(0, B0s);

  // ---- steady K-loop (tiles 0 .. NT-2) ----
  for (int s = 0; s < NT - 1; s++) {
    int ks2 = ks + 1, tt2 = tt;
    if (ks2 == nks) { ks2 = 0; tt2++; }
    const u16* sA = xrow + (size_t)tt2 * (256 * CINP) + ks2 * 64;
    const u16* sB = Wg + ks2 * 64;
    u16* cA = (s & 1) ? A1s : A0s;
    u16* cB = (s & 1) ? B1s : B0s;
    u16* nA = (s & 1) ? A0s : A1s;
    u16* nB = (s & 1) ? B0s : B1s;

    // ph1
    STAGE(sA, CINP, nA, 0);
    BAR();
    MFMAQ(0, 0, afrA);
    VM2;                     // certify cur A-h1 (for ph2-tail)
    READ_B(1, cB);           // cur B-h1 (certified at prev ph4-end)
    BAR();
    // ph2
    STAGE(sB, Kp, nB, 0);
    BAR();
    MFMAQ(0, 1, afrA);
    READ_A(afrB, cA, 1);     // cur A-h1 (certified at ph1-end)
    BAR();
    // ph3
    STAGE(sB, Kp, nB, 1);
    BAR();
    MFMAQ(1, 0, afrB);
    VM2;                     // certify nA-h0, nB-h0 (for ph4-tail)
    BAR();
    // ph4
    STAGE(sA, CINP, nA, 1);
    BAR();
    MFMAQ(1, 1, afrB);
    VM2;                     // certify nB-h1 (for next ph1-tail)
    READ_A(afrA, nA, 0);     // next A-h0 (certified at ph3-end)
    READ_B(0, nB);           // next B-h0 (certified at ph3-end)
    BAR();

    if (++ks == nks) { FOLD(tt); ks = 0; tt++; }
  }

  // ---- peeled last tile (reads buf1; no staging; drain to 0) ----
  {
    MFMAQ(0, 0, afrA);
    VM0;                     // certify A-h1 (last outstanding)
    READ_B(1, B1s);          // B-h1 (certified at last steady ph4-end)
    BAR();
    MFMAQ(0, 1, afrA);
    READ_A(afrB, A1s, 1);    // A-h1 (certified at VM0 + BAR)
    MFMAQ(1, 0, afrB);
    MFMAQ(1, 1, afrB);
    FOLD(tt);
  }
#undef READ_A
#undef READ_B
#undef MFMAQ

  // ---- epilogue: intra-wave max, cross-wave (wr pair) combine, bias+relu ----
  float cv[4];
  #pragma unroll
  for (int ni = 0; ni < 4; ni++) {
    float v = rmax[ni];
    v = fmaxf(v, __shfl_xor(v, 16));
    v = fmaxf(v, __shfl_xor(v, 32));
    cv[ni] = v;
  }
  __syncthreads();                    // full drain; smem reusable
  float* red = (float*)smem;          // 512 floats: [wr][gn*16 + col]
  if (lane < 16) {
    #pragma unroll
    for (int ni = 0; ni < 4; ni++)
      red[wr * 256 + (ni * 4 + wc) * 16 + lane] = cv[ni];
  }
  __syncthreads();
  const float* bias = (g == 0) ? b2v : (g == 1) ? b3v : b4v;
  if (tid < 256) {
    float v = fmaxf(red[tid], red[256 + tid]);
    int ch = chblk * BN + tid;
    if (ch < NCH) {
      int n = ch / ODIM, o = ch - n * ODIM;
      out[b * (ODIM * 180) + o * 180 + g * 60 + n] = fmaxf(v + bias[ch], 0.f);
    }
  }
}

extern "C" void kernel_launch(void* const* d_in, const int* in_sizes, int n_in,
                              void* d_out, int out_size, void* d_ws, size_t ws_size,
                              hipStream_t stream) {
  const float* x  = (const float*)d_in[0];
  const float* W2 = (const float*)d_in[1];
  const float* b2 = (const float*)d_in[2];
  const float* W3 = (const float*)d_in[3];
  const float* b3 = (const float*)d_in[4];
  const float* W4 = (const float*)d_in[5];
  const float* b4 = (const float*)d_in[6];
  float* out = (float*)d_out;

  u16* xb = (u16*)d_ws;            // XELP bf16 (10.5 MB)
  u16* wb = xb + XELP;             // NCHP*(640+960+1280) bf16 (35.4 MB)

  prep_kernel<<<3 * NCHP + XELP / (256 * 8), 256, 0, stream>>>(x, W2, W3, W4, xb, wb);
  gemm_max_kernel<<<dim3(1152), 512, 0, stream>>>(xb, wb, b2, b3, b4, out);
}

// Round 11
// 527.891 us; speedup vs baseline: 1.6897x; 1.0066x over previous
//
#include <hip/hip_runtime.h>
#include <cstdint>
#include <cstddef>

typedef unsigned short u16;
typedef unsigned int   u32;
typedef __attribute__((ext_vector_type(8))) short bf16x8;
typedef __attribute__((ext_vector_type(4))) float f32x4;

#define NB   16
#define LL   1024
#define CIN  300
#define CINP 320              /* padded channels: rows 640B, 16B aligned */
#define XPBP (LL*CINP)        /* 327680 elems per batch */
#define XELP (NB*XPBP)        /* 5242880 */
#define NCH  6000
#define NCHP 6144             /* padded to 24*256 */
#define ODIM 100

#define BM 256
#define BN 256
#define BK 64

__device__ __forceinline__ u16 f2bf(float f) {
  union { float f; u32 u; } v; v.f = f;
  return (u16)((v.u + 0x7FFFu + ((v.u >> 16) & 1u)) >> 16);   // RNE, inputs finite
}

typedef __attribute__((address_space(1))) const unsigned int gu32;
typedef __attribute__((address_space(3))) unsigned int lu32;
__device__ __forceinline__ void gload_lds16(const void* g, void* l) {
  __builtin_amdgcn_global_load_lds((gu32*)g, (lu32*)l, 16, 0, 0);
}

#define BAR() asm volatile("s_barrier" ::: "memory")
#define VM2  asm volatile("s_waitcnt vmcnt(2)" ::: "memory")
#define VM0  asm volatile("s_waitcnt vmcnt(0)" ::: "memory")

// ---- merged prep: repack W (blocks 0..18431) + cvt x (blocks 18432..20991)
__global__ void prep_kernel(const float* __restrict__ x,
                            const float* __restrict__ W2, const float* __restrict__ W3,
                            const float* __restrict__ W4,
                            u16* __restrict__ xb, u16* __restrict__ wb) {
  int bid = blockIdx.x;
  if (bid < 3 * NCHP) {
    // W[n,o,c,j] f32 -> Wb[no][kp = j*320 + c] bf16 (zeros c>=300, no>=6000)
    int g  = bid / NCHP;
    int no = bid - g * NCHP;                   // 0..6143
    int kk = g + 2;
    int Kp = kk * CINP;
    int woff = (g == 0) ? 0 : (g == 1) ? NCHP*640 : NCHP*(640+960);
    const float* W = (g == 0) ? W2 : (g == 1) ? W3 : W4;
    u16* dst = wb + (size_t)woff + (size_t)no * Kp;
    const float* src = W + (size_t)no * (CIN * kk);
    for (int kp = threadIdx.x; kp < Kp; kp += 256) {
      int j = kp / CINP, c = kp - j * CINP;
      u16 v = 0;
      if (no < NCH && c < CIN) v = f2bf(src[c * kk + j]);
      dst[kp] = v;
    }
  } else {
    // x [16,1024,300] f32 -> xb [16,1024,320] bf16 (zero-pad channels)
    int i8 = ((bid - 3 * NCHP) * 256 + threadIdx.x) * 8;   // 2560 blocks
    int row = i8 / CINP;
    int col = i8 - row * CINP;
    const float* src = x + (size_t)row * CIN + col;
    u16 e[8];
    if (col + 8 <= CIN) {
      float4 a = *(const float4*)src;
      float4 b = *(const float4*)(src + 4);
      e[0]=f2bf(a.x); e[1]=f2bf(a.y); e[2]=f2bf(a.z); e[3]=f2bf(a.w);
      e[4]=f2bf(b.x); e[5]=f2bf(b.y); e[6]=f2bf(b.z); e[7]=f2bf(b.w);
    } else {
      #pragma unroll
      for (int j = 0; j < 8; j++)
        e[j] = (col + j < CIN) ? f2bf(src[j]) : (u16)0;
    }
    uint4 o;
    o.x = (u32)e[0] | ((u32)e[1] << 16);
    o.y = (u32)e[2] | ((u32)e[3] << 16);
    o.z = (u32)e[4] | ((u32)e[5] << 16);
    o.w = (u32)e[6] | ((u32)e[7] << 16);
    *(uint4*)(xb + i8) = o;
  }
}

// ---- fused GEMM + running-max + bias + relu ------------------------------
// 256^2 8-phase (T2+T3+T4+T5), TAIL-READ schedule (r7) with reads HOISTED
// ABOVE the phase's VM2 fence (legal: each read's buffer was certified one
// barrier earlier; the VM2 only gates LATER phases' reads). This lets the
// compiler interleave next-phase ds_reads into the current MFMA cluster.
// Certification chain unchanged:
//   ph3-end vmcnt(2) -> {nA0,nB0} certified for ph4 reads
//   ph4-end vmcnt(2) -> {nB1}     certified for next ph1 read
//   ph1-end vmcnt(2) -> {cur A1}  certified for ph2 read
__global__ __launch_bounds__(512, 1)
void gemm_max_kernel(const u16* __restrict__ xb, const u16* __restrict__ wb,
                     const float* __restrict__ b2v, const float* __restrict__ b3v,
                     const float* __restrict__ b4v, float* __restrict__ out) {
  // LPT remap: ids 0..383 -> g=2, 384..767 -> g=1, 768..1151 -> g=0
  const int id    = blockIdx.x;
  const int g     = 2 - (id / 384);
  const int id2   = id % 384;
  const int b     = id2 / 24;      // 0..15
  const int chblk = id2 % 24;      // 0..23
  const int Kp    = (g + 2) * CINP;                 // 640 / 960 / 1280
  const int nks   = Kp >> 6;                        // 10 / 15 / 20
  const int woff  = (g == 0) ? 0 : (g == 1) ? NCHP*640 : NCHP*(640+960);
  const int Lt    = LL - (g + 2) + 1;

  __shared__ __align__(16) u16 smem[4 * 16384];     // 128 KiB
  u16* A0s = smem;
  u16* B0s = smem + 16384;
  u16* A1s = smem + 32768;
  u16* B1s = smem + 49152;

  const int tid  = threadIdx.x;
  const int lane = tid & 63;
  const int w    = tid >> 6;       // 0..7
  const int wr   = w >> 2;         // 0..1 : M interleave
  const int wc   = w & 3;          // 0..3 : N interleave

  const u16* __restrict__ xrow = xb + (size_t)b * XPBP;
  const u16* __restrict__ Wg   = wb + (size_t)woff + (size_t)chblk * BN * Kp;

  // stage one 128x64 half: linear LDS dest (wave-uniform base), inverse-swizzled src
  auto STAGE = [&](const u16* src, int stride, u16* buf, int half) {
    #pragma unroll
    for (int i = 0; i < 2; i++) {
      int c = i * 512 + w * 64 + lane;                  // chunk 0..1023
      int row128 = c >> 3;
      int colb = ((c & 7) * 16) ^ ((row128 & 7) << 4);  // inverse swizzle (involution)
      gload_lds16(src + (size_t)(half * 128 + row128) * stride + (colb >> 1),
                  buf + half * 8192 + i * 4096 + w * 512);
    }
  };

  // swizzled fragment read: group grp (16 rows), ksub k
  auto FR = [&](const u16* buf, int grp, int k) -> bf16x8 {
    int row  = grp * 16 + (lane & 15);
    int colb = (k * 64 + ((lane >> 4) << 4)) ^ ((lane & 7) << 4);  // row&7 == lane&7
    return *(const bf16x8*)(buf + row * 64 + (colb >> 1));
  };

  f32x4 acc[8][4];
  #pragma unroll
  for (int mi = 0; mi < 8; mi++)
    #pragma unroll
    for (int ni = 0; ni < 4; ni++)
      acc[mi][ni] = (f32x4){0.f, 0.f, 0.f, 0.f};

  bf16x8 afrA[4][2];      // A-half-0 frags (used ph1, ph2)
  bf16x8 afrB[4][2];      // A-half-1 frags (used ph3, ph4)
  bf16x8 bfr[2][2][2];    // [nh][b2][k2]
  float rmax[4] = { -1e30f, -1e30f, -1e30f, -1e30f };

  auto FOLD = [&](int ttf) {
    #pragma unroll
    for (int mi = 0; mi < 8; mi++) {
      int tb = ttf * 256 + (mi * 2 + wr) * 16 + ((lane >> 4) << 2);
      #pragma unroll
      for (int r = 0; r < 4; r++) {
        bool ok = (tb + r) < Lt;
        #pragma unroll
        for (int ni = 0; ni < 4; ni++)
          if (ok) rmax[ni] = fmaxf(rmax[ni], acc[mi][ni][r]);
      }
      #pragma unroll
      for (int ni = 0; ni < 4; ni++)
        acc[mi][ni] = (f32x4){0.f, 0.f, 0.f, 0.f};
    }
  };

#define READ_A(DST, BUF, MH) do {                                             \
    _Pragma("unroll")                                                         \
    for (int a2 = 0; a2 < 4; a2++) {                                          \
      _Pragma("unroll")                                                       \
      for (int k2 = 0; k2 < 2; k2++)                                          \
        DST[a2][k2] = FR(BUF, ((MH)*4 + a2) * 2 + wr, k2);                    \
    }                                                                         \
  } while (0)

#define READ_B(NH, BUF) do {                                                  \
    _Pragma("unroll")                                                         \
    for (int b2 = 0; b2 < 2; b2++) {                                          \
      _Pragma("unroll")                                                       \
      for (int k2 = 0; k2 < 2; k2++)                                          \
        bfr[NH][b2][k2] = FR(BUF, ((NH)*2 + b2) * 4 + wc, k2);                \
    }                                                                         \
  } while (0)

#define MFMAQ(MH, NH, A) do {                                                 \
    __builtin_amdgcn_s_setprio(1);                                            \
    _Pragma("unroll")                                                         \
    for (int a2 = 0; a2 < 4; a2++)                                            \
      _Pragma("unroll")                                                       \
      for (int b2 = 0; b2 < 2; b2++)                                          \
        _Pragma("unroll")                                                     \
        for (int k2 = 0; k2 < 2; k2++)                                        \
          acc[(MH)*4 + a2][(NH)*2 + b2] =                                     \
            __builtin_amdgcn_mfma_f32_16x16x32_bf16(A[a2][k2],                \
              bfr[NH][b2][k2], acc[(MH)*4 + a2][(NH)*2 + b2], 0, 0, 0);       \
    __builtin_amdgcn_s_setprio(0);                                            \
  } while (0)

  const int NT = 4 * nks;    // 40 / 60 / 80 (always even)
  int tt = 0, ks = 0;

  // ---- prologue: tile0 -> buf0, order [A-h0, B-h0, B-h1, A-h1] ----
  STAGE(xrow, CINP, A0s, 0);
  STAGE(Wg,   Kp,   B0s, 0);
  STAGE(Wg,   Kp,   B0s, 1);
  STAGE(xrow, CINP, A0s, 1);
  VM2;                       // A-h0, B-h0, B-h1 certified (A-h1 outstanding)
  BAR();
  READ_A(afrA, A0s, 0);
  READ_B(0, B0s);

  // ---- steady K-loop (tiles 0 .. NT-2) ----
  for (int s = 0; s < NT - 1; s++) {
    int ks2 = ks + 1, tt2 = tt;
    if (ks2 == nks) { ks2 = 0; tt2++; }
    const u16* sA = xrow + (size_t)tt2 * (256 * CINP) + ks2 * 64;
    const u16* sB = Wg + ks2 * 64;
    u16* cA = (s & 1) ? A1s : A0s;
    u16* cB = (s & 1) ? B1s : B0s;
    u16* nA = (s & 1) ? A0s : A1s;
    u16* nB = (s & 1) ? B0s : B1s;

    // ph1  (read before VM2: cB-h1 was certified at prev ph4-end)
    STAGE(sA, CINP, nA, 0);
    BAR();
    MFMAQ(0, 0, afrA);
    READ_B(1, cB);           // overlappable with MFMA cluster above
    VM2;                     // certify cur A-h1 (for ph2 read)
    BAR();
    // ph2  (already fence-free)
    STAGE(sB, Kp, nB, 0);
    BAR();
    MFMAQ(0, 1, afrA);
    READ_A(afrB, cA, 1);     // cur A-h1 (certified at ph1-end)
    BAR();
    // ph3
    STAGE(sB, Kp, nB, 1);
    BAR();
    MFMAQ(1, 0, afrB);
    VM2;                     // certify nA-h0, nB-h0 (for ph4 reads)
    BAR();
    // ph4  (reads before VM2: nA-h0/nB-h0 certified at ph3-end)
    STAGE(sA, CINP, nA, 1);
    BAR();
    MFMAQ(1, 1, afrB);
    READ_A(afrA, nA, 0);     // overlappable with MFMA cluster above
    READ_B(0, nB);
    VM2;                     // certify nB-h1 (for next ph1 read)
    BAR();

    if (++ks == nks) { FOLD(tt); ks = 0; tt++; }
  }

  // ---- peeled last tile (reads buf1; no staging; drain to 0) ----
  {
    MFMAQ(0, 0, afrA);
    READ_B(1, B1s);          // certified at last steady ph4-end
    VM0;                     // certify A1s (last outstanding stage)
    BAR();
    MFMAQ(0, 1, afrA);
    READ_A(afrB, A1s, 1);    // A-h1 (certified at VM0 + BAR)
    MFMAQ(1, 0, afrB);
    MFMAQ(1, 1, afrB);
    FOLD(tt);
  }
#undef READ_A
#undef READ_B
#undef MFMAQ

  // ---- epilogue: intra-wave max, cross-wave (wr pair) combine, bias+relu ----
  float cv[4];
  #pragma unroll
  for (int ni = 0; ni < 4; ni++) {
    float v = rmax[ni];
    v = fmaxf(v, __shfl_xor(v, 16));
    v = fmaxf(v, __shfl_xor(v, 32));
    cv[ni] = v;
  }
  __syncthreads();                    // full drain; smem reusable
  float* red = (float*)smem;          // 512 floats: [wr][gn*16 + col]
  if (lane < 16) {
    #pragma unroll
    for (int ni = 0; ni < 4; ni++)
      red[wr * 256 + (ni * 4 + wc) * 16 + lane] = cv[ni];
  }
  __syncthreads();
  const float* bias = (g == 0) ? b2v : (g == 1) ? b3v : b4v;
  if (tid < 256) {
    float v = fmaxf(red[tid], red[256 + tid]);
    int ch = chblk * BN + tid;
    if (ch < NCH) {
      int n = ch / ODIM, o = ch - n * ODIM;
      out[b * (ODIM * 180) + o * 180 + g * 60 + n] = fmaxf(v + bias[ch], 0.f);
    }
  }
}

extern "C" void kernel_launch(void* const* d_in, const int* in_sizes, int n_in,
                              void* d_out, int out_size, void* d_ws, size_t ws_size,
                              hipStream_t stream) {
  const float* x  = (const float*)d_in[0];
  const float* W2 = (const float*)d_in[1];
  const float* b2 = (const float*)d_in[2];
  const float* W3 = (const float*)d_in[3];
  const float* b3 = (const float*)d_in[4];
  const float* W4 = (const float*)d_in[5];
  const float* b4 = (const float*)d_in[6];
  float* out = (float*)d_out;

  u16* xb = (u16*)d_ws;            // XELP bf16 (10.5 MB)
  u16* wb = xb + XELP;             // NCHP*(640+960+1280) bf16 (35.4 MB)

  prep_kernel<<<3 * NCHP + XELP / (256 * 8), 256, 0, stream>>>(x, W2, W3, W4, xb, wb);
  gemm_max_kernel<<<dim3(1152), 512, 0, stream>>>(xb, wb, b2, b3, b4, out);
}

// Round 12
// 505.428 us; speedup vs baseline: 1.7648x; 1.0444x over previous
//
#include <hip/hip_runtime.h>
#include <cstdint>
#include <cstddef>

typedef unsigned short u16;
typedef unsigned int   u32;
typedef __attribute__((ext_vector_type(8))) short bf16x8;
typedef __attribute__((ext_vector_type(4))) float f32x4;

#define NB   16
#define LL   1024
#define CIN  300
#define CINP 320              /* padded channels: rows 640B, 16B aligned */
#define XPBP (LL*CINP)        /* 327680 elems per batch */
#define XELP (NB*XPBP)        /* 5242880 */
#define NCH  6000
#define NCHP 6144             /* padded to 24*256 */
#define ODIM 100

#define BM 256
#define BN 256
#define BK 64

__device__ __forceinline__ u16 f2bf(float f) {
  union { float f; u32 u; } v; v.f = f;
  return (u16)((v.u + 0x7FFFu + ((v.u >> 16) & 1u)) >> 16);   // RNE, inputs finite
}

typedef __attribute__((address_space(1))) const unsigned int gu32;
typedef __attribute__((address_space(3))) unsigned int lu32;
__device__ __forceinline__ void gload_lds16(const void* g, void* l) {
  __builtin_amdgcn_global_load_lds((gu32*)g, (lu32*)l, 16, 0, 0);
}

#define BAR() asm volatile("s_barrier" ::: "memory")
#define VM2  asm volatile("s_waitcnt vmcnt(2)" ::: "memory")
#define VM0  asm volatile("s_waitcnt vmcnt(0)" ::: "memory")

// ---- merged prep: repack W (blocks 0..18431) + cvt x (blocks 18432..20991)
__global__ void prep_kernel(const float* __restrict__ x,
                            const float* __restrict__ W2, const float* __restrict__ W3,
                            const float* __restrict__ W4,
                            u16* __restrict__ xb, u16* __restrict__ wb) {
  int bid = blockIdx.x;
  if (bid < 3 * NCHP) {
    // W[n,o,c,j] f32 -> Wb[no][kp = j*320 + c] bf16 (zeros c>=300, no>=6000)
    int g  = bid / NCHP;
    int no = bid - g * NCHP;                   // 0..6143
    int kk = g + 2;
    int Kp = kk * CINP;
    int woff = (g == 0) ? 0 : (g == 1) ? NCHP*640 : NCHP*(640+960);
    const float* W = (g == 0) ? W2 : (g == 1) ? W3 : W4;
    u16* dst = wb + (size_t)woff + (size_t)no * Kp;
    const float* src = W + (size_t)no * (CIN * kk);
    for (int kp = threadIdx.x; kp < Kp; kp += 256) {
      int j = kp / CINP, c = kp - j * CINP;
      u16 v = 0;
      if (no < NCH && c < CIN) v = f2bf(src[c * kk + j]);
      dst[kp] = v;
    }
  } else {
    // x [16,1024,300] f32 -> xb [16,1024,320] bf16 (zero-pad channels)
    int i8 = ((bid - 3 * NCHP) * 256 + threadIdx.x) * 8;   // 2560 blocks
    int row = i8 / CINP;
    int col = i8 - row * CINP;
    const float* src = x + (size_t)row * CIN + col;
    u16 e[8];
    if (col + 8 <= CIN) {
      float4 a = *(const float4*)src;
      float4 b = *(const float4*)(src + 4);
      e[0]=f2bf(a.x); e[1]=f2bf(a.y); e[2]=f2bf(a.z); e[3]=f2bf(a.w);
      e[4]=f2bf(b.x); e[5]=f2bf(b.y); e[6]=f2bf(b.z); e[7]=f2bf(b.w);
    } else {
      #pragma unroll
      for (int j = 0; j < 8; j++)
        e[j] = (col + j < CIN) ? f2bf(src[j]) : (u16)0;
    }
    uint4 o;
    o.x = (u32)e[0] | ((u32)e[1] << 16);
    o.y = (u32)e[2] | ((u32)e[3] << 16);
    o.z = (u32)e[4] | ((u32)e[5] << 16);
    o.w = (u32)e[6] | ((u32)e[7] << 16);
    *(uint4*)(xb + i8) = o;
  }
}

// ---- fused GEMM + running-max + bias + relu ------------------------------
// 256^2 8-phase tail-read schedule (r7/r11, verified) with the 4 REDUNDANT
// OPENING BARRIERS DELETED (4 barriers/K-step, close-barriers only).
// Audit (r12): certification carried entirely by VM2+close-BAR pairs
// (identical queue counts to r7); WAR gaps on every buffer half are >= 1
// full K-step; max wave skew = 1 region, and no region touches the buffer
// a 1-region-ahead wave stages (opposite parity or different half).
//   ph3-end vmcnt(2)+BAR -> {nA0,nB0} certified for ph4-tail reads
//   ph4-end vmcnt(2)+BAR -> {nB1}     certified for next ph1-tail read
//   ph1-end vmcnt(2)+BAR -> {cur A1}  certified for ph2-tail read
__global__ __launch_bounds__(512, 1)
void gemm_max_kernel(const u16* __restrict__ xb, const u16* __restrict__ wb,
                     const float* __restrict__ b2v, const float* __restrict__ b3v,
                     const float* __restrict__ b4v, float* __restrict__ out) {
  // LPT remap: ids 0..383 -> g=2, 384..767 -> g=1, 768..1151 -> g=0
  const int id    = blockIdx.x;
  const int g     = 2 - (id / 384);
  const int id2   = id % 384;
  const int b     = id2 / 24;      // 0..15
  const int chblk = id2 % 24;      // 0..23
  const int Kp    = (g + 2) * CINP;                 // 640 / 960 / 1280
  const int nks   = Kp >> 6;                        // 10 / 15 / 20
  const int woff  = (g == 0) ? 0 : (g == 1) ? NCHP*640 : NCHP*(640+960);
  const int Lt    = LL - (g + 2) + 1;

  __shared__ __align__(16) u16 smem[4 * 16384];     // 128 KiB
  u16* A0s = smem;
  u16* B0s = smem + 16384;
  u16* A1s = smem + 32768;
  u16* B1s = smem + 49152;

  const int tid  = threadIdx.x;
  const int lane = tid & 63;
  const int w    = tid >> 6;       // 0..7
  const int wr   = w >> 2;         // 0..1 : M interleave
  const int wc   = w & 3;          // 0..3 : N interleave

  const u16* __restrict__ xrow = xb + (size_t)b * XPBP;
  const u16* __restrict__ Wg   = wb + (size_t)woff + (size_t)chblk * BN * Kp;

  // stage one 128x64 half: linear LDS dest (wave-uniform base), inverse-swizzled src
  auto STAGE = [&](const u16* src, int stride, u16* buf, int half) {
    #pragma unroll
    for (int i = 0; i < 2; i++) {
      int c = i * 512 + w * 64 + lane;                  // chunk 0..1023
      int row128 = c >> 3;
      int colb = ((c & 7) * 16) ^ ((row128 & 7) << 4);  // inverse swizzle (involution)
      gload_lds16(src + (size_t)(half * 128 + row128) * stride + (colb >> 1),
                  buf + half * 8192 + i * 4096 + w * 512);
    }
  };

  // swizzled fragment read: group grp (16 rows), ksub k
  auto FR = [&](const u16* buf, int grp, int k) -> bf16x8 {
    int row  = grp * 16 + (lane & 15);
    int colb = (k * 64 + ((lane >> 4) << 4)) ^ ((lane & 7) << 4);  // row&7 == lane&7
    return *(const bf16x8*)(buf + row * 64 + (colb >> 1));
  };

  f32x4 acc[8][4];
  #pragma unroll
  for (int mi = 0; mi < 8; mi++)
    #pragma unroll
    for (int ni = 0; ni < 4; ni++)
      acc[mi][ni] = (f32x4){0.f, 0.f, 0.f, 0.f};

  bf16x8 afrA[4][2];      // A-half-0 frags (used ph1, ph2)
  bf16x8 afrB[4][2];      // A-half-1 frags (used ph3, ph4)
  bf16x8 bfr[2][2][2];    // [nh][b2][k2]
  float rmax[4] = { -1e30f, -1e30f, -1e30f, -1e30f };

  auto FOLD = [&](int ttf) {
    #pragma unroll
    for (int mi = 0; mi < 8; mi++) {
      int tb = ttf * 256 + (mi * 2 + wr) * 16 + ((lane >> 4) << 2);
      #pragma unroll
      for (int r = 0; r < 4; r++) {
        bool ok = (tb + r) < Lt;
        #pragma unroll
        for (int ni = 0; ni < 4; ni++)
          if (ok) rmax[ni] = fmaxf(rmax[ni], acc[mi][ni][r]);
      }
      #pragma unroll
      for (int ni = 0; ni < 4; ni++)
        acc[mi][ni] = (f32x4){0.f, 0.f, 0.f, 0.f};
    }
  };

#define READ_A(DST, BUF, MH) do {                                             \
    _Pragma("unroll")                                                         \
    for (int a2 = 0; a2 < 4; a2++) {                                          \
      _Pragma("unroll")                                                       \
      for (int k2 = 0; k2 < 2; k2++)                                          \
        DST[a2][k2] = FR(BUF, ((MH)*4 + a2) * 2 + wr, k2);                    \
    }                                                                         \
  } while (0)

#define READ_B(NH, BUF) do {                                                  \
    _Pragma("unroll")                                                         \
    for (int b2 = 0; b2 < 2; b2++) {                                          \
      _Pragma("unroll")                                                       \
      for (int k2 = 0; k2 < 2; k2++)                                          \
        bfr[NH][b2][k2] = FR(BUF, ((NH)*2 + b2) * 4 + wc, k2);                \
    }                                                                         \
  } while (0)

#define MFMAQ(MH, NH, A) do {                                                 \
    __builtin_amdgcn_s_setprio(1);                                            \
    _Pragma("unroll")                                                         \
    for (int a2 = 0; a2 < 4; a2++)                                            \
      _Pragma("unroll")                                                       \
      for (int b2 = 0; b2 < 2; b2++)                                          \
        _Pragma("unroll")                                                     \
        for (int k2 = 0; k2 < 2; k2++)                                        \
          acc[(MH)*4 + a2][(NH)*2 + b2] =                                     \
            __builtin_amdgcn_mfma_f32_16x16x32_bf16(A[a2][k2],                \
              bfr[NH][b2][k2], acc[(MH)*4 + a2][(NH)*2 + b2], 0, 0, 0);       \
    __builtin_amdgcn_s_setprio(0);                                            \
  } while (0)

  const int NT = 4 * nks;    // 40 / 60 / 80 (always even)
  int tt = 0, ks = 0;

  // ---- prologue: tile0 -> buf0, order [A-h0, B-h0, B-h1, A-h1] ----
  STAGE(xrow, CINP, A0s, 0);
  STAGE(Wg,   Kp,   B0s, 0);
  STAGE(Wg,   Kp,   B0s, 1);
  STAGE(xrow, CINP, A0s, 1);
  VM2;                       // A-h0, B-h0, B-h1 certified (A-h1 outstanding)
  BAR();
  READ_A(afrA, A0s, 0);
  READ_B(0, B0s);

  // ---- steady K-loop (tiles 0 .. NT-2), close-barriers only ----
  for (int s = 0; s < NT - 1; s++) {
    int ks2 = ks + 1, tt2 = tt;
    if (ks2 == nks) { ks2 = 0; tt2++; }
    const u16* sA = xrow + (size_t)tt2 * (256 * CINP) + ks2 * 64;
    const u16* sB = Wg + ks2 * 64;
    u16* cA = (s & 1) ? A1s : A0s;
    u16* cB = (s & 1) ? B1s : B0s;
    u16* nA = (s & 1) ? A0s : A1s;
    u16* nB = (s & 1) ? B0s : B1s;

    // ph1
    STAGE(sA, CINP, nA, 0);
    MFMAQ(0, 0, afrA);
    READ_B(1, cB);           // cur B-h1 (certified at prev ph4-end)
    VM2;                     // certify cur A-h1 (for ph2 read)
    BAR();
    // ph2
    STAGE(sB, Kp, nB, 0);
    MFMAQ(0, 1, afrA);
    READ_A(afrB, cA, 1);     // cur A-h1 (certified at ph1-end)
    BAR();
    // ph3
    STAGE(sB, Kp, nB, 1);
    MFMAQ(1, 0, afrB);
    VM2;                     // certify nA-h0, nB-h0 (for ph4 reads)
    BAR();
    // ph4
    STAGE(sA, CINP, nA, 1);
    MFMAQ(1, 1, afrB);
    READ_A(afrA, nA, 0);     // next A-h0 (certified at ph3-end)
    READ_B(0, nB);           // next B-h0 (certified at ph3-end)
    VM2;                     // certify nB-h1 (for next ph1 read)
    BAR();

    if (++ks == nks) { FOLD(tt); ks = 0; tt++; }
  }

  // ---- peeled last tile (reads buf1; no staging; drain to 0) ----
  {
    MFMAQ(0, 0, afrA);
    READ_B(1, B1s);          // certified at last steady ph4-end
    VM0;                     // certify A1s (last outstanding stage)
    BAR();
    MFMAQ(0, 1, afrA);
    READ_A(afrB, A1s, 1);    // A-h1 (certified at VM0 + BAR)
    MFMAQ(1, 0, afrB);
    MFMAQ(1, 1, afrB);
    FOLD(tt);
  }
#undef READ_A
#undef READ_B
#undef MFMAQ

  // ---- epilogue: intra-wave max, cross-wave (wr pair) combine, bias+relu ----
  float cv[4];
  #pragma unroll
  for (int ni = 0; ni < 4; ni++) {
    float v = rmax[ni];
    v = fmaxf(v, __shfl_xor(v, 16));
    v = fmaxf(v, __shfl_xor(v, 32));
    cv[ni] = v;
  }
  __syncthreads();                    // full drain; smem reusable
  float* red = (float*)smem;          // 512 floats: [wr][gn*16 + col]
  if (lane < 16) {
    #pragma unroll
    for (int ni = 0; ni < 4; ni++)
      red[wr * 256 + (ni * 4 + wc) * 16 + lane] = cv[ni];
  }
  __syncthreads();
  const float* bias = (g == 0) ? b2v : (g == 1) ? b3v : b4v;
  if (tid < 256) {
    float v = fmaxf(red[tid], red[256 + tid]);
    int ch = chblk * BN + tid;
    if (ch < NCH) {
      int n = ch / ODIM, o = ch - n * ODIM;
      out[b * (ODIM * 180) + o * 180 + g * 60 + n] = fmaxf(v + bias[ch], 0.f);
    }
  }
}

extern "C" void kernel_launch(void* const* d_in, const int* in_sizes, int n_in,
                              void* d_out, int out_size, void* d_ws, size_t ws_size,
                              hipStream_t stream) {
  const float* x  = (const float*)d_in[0];
  const float* W2 = (const float*)d_in[1];
  const float* b2 = (const float*)d_in[2];
  const float* W3 = (const float*)d_in[3];
  const float* b3 = (const float*)d_in[4];
  const float* W4 = (const float*)d_in[5];
  const float* b4 = (const float*)d_in[6];
  float* out = (float*)d_out;

  u16* xb = (u16*)d_ws;            // XELP bf16 (10.5 MB)
  u16* wb = xb + XELP;             // NCHP*(640+960+1280) bf16 (35.4 MB)

  prep_kernel<<<3 * NCHP + XELP / (256 * 8), 256, 0, stream>>>(x, W2, W3, W4, xb, wb);
  gemm_max_kernel<<<dim3(1152), 512, 0, stream>>>(xb, wb, b2, b3, b4, out);
}

// Round 13
// 481.985 us; speedup vs baseline: 1.8506x; 1.0486x over previous
//
#include <hip/hip_runtime.h>
#include <cstdint>
#include <cstddef>

typedef unsigned short u16;
typedef unsigned int   u32;
typedef __attribute__((ext_vector_type(8))) short bf16x8;
typedef __attribute__((ext_vector_type(4))) float f32x4;

#define NB   16
#define LL   1024
#define CIN  300
#define CINP 320              /* padded channels: rows 640B, 16B aligned */
#define XPBP (LL*CINP)        /* 327680 elems per batch */
#define XELP (NB*XPBP)        /* 5242880 */
#define NCH  6000
#define NCHP 6144             /* padded to 24*256 */
#define ODIM 100

#define BM 256
#define BN 256
#define BK 64

__device__ __forceinline__ u16 f2bf(float f) {
  union { float f; u32 u; } v; v.f = f;
  return (u16)((v.u + 0x7FFFu + ((v.u >> 16) & 1u)) >> 16);   // RNE, inputs finite
}

typedef __attribute__((address_space(1))) const unsigned int gu32;
typedef __attribute__((address_space(3))) unsigned int lu32;
__device__ __forceinline__ void gload_lds16(const void* g, void* l) {
  __builtin_amdgcn_global_load_lds((gu32*)g, (lu32*)l, 16, 0, 0);
}

#define BAR() asm volatile("s_barrier" ::: "memory")
#define VM2  asm volatile("s_waitcnt vmcnt(2)" ::: "memory")
#define VM0  asm volatile("s_waitcnt vmcnt(0)" ::: "memory")

// ---- merged prep: repack W (blocks 0..18431) + cvt x (blocks 18432..20991)
__global__ void prep_kernel(const float* __restrict__ x,
                            const float* __restrict__ W2, const float* __restrict__ W3,
                            const float* __restrict__ W4,
                            u16* __restrict__ xb, u16* __restrict__ wb) {
  int bid = blockIdx.x;
  if (bid < 3 * NCHP) {
    // W[n,o,c,j] f32 -> Wb[no][kp = j*320 + c] bf16 (zeros c>=300, no>=6000)
    int g  = bid / NCHP;
    int no = bid - g * NCHP;                   // 0..6143
    int kk = g + 2;
    int Kp = kk * CINP;
    int woff = (g == 0) ? 0 : (g == 1) ? NCHP*640 : NCHP*(640+960);
    const float* W = (g == 0) ? W2 : (g == 1) ? W3 : W4;
    u16* dst = wb + (size_t)woff + (size_t)no * Kp;
    const float* src = W + (size_t)no * (CIN * kk);
    for (int kp = threadIdx.x; kp < Kp; kp += 256) {
      int j = kp / CINP, c = kp - j * CINP;
      u16 v = 0;
      if (no < NCH && c < CIN) v = f2bf(src[c * kk + j]);
      dst[kp] = v;
    }
  } else {
    // x [16,1024,300] f32 -> xb [16,1024,320] bf16 (zero-pad channels)
    int i8 = ((bid - 3 * NCHP) * 256 + threadIdx.x) * 8;   // 2560 blocks
    int row = i8 / CINP;
    int col = i8 - row * CINP;
    const float* src = x + (size_t)row * CIN + col;
    u16 e[8];
    if (col + 8 <= CIN) {
      float4 a = *(const float4*)src;
      float4 b = *(const float4*)(src + 4);
      e[0]=f2bf(a.x); e[1]=f2bf(a.y); e[2]=f2bf(a.z); e[3]=f2bf(a.w);
      e[4]=f2bf(b.x); e[5]=f2bf(b.y); e[6]=f2bf(b.z); e[7]=f2bf(b.w);
    } else {
      #pragma unroll
      for (int j = 0; j < 8; j++)
        e[j] = (col + j < CIN) ? f2bf(src[j]) : (u16)0;
    }
    uint4 o;
    o.x = (u32)e[0] | ((u32)e[1] << 16);
    o.y = (u32)e[2] | ((u32)e[3] << 16);
    o.z = (u32)e[4] | ((u32)e[5] << 16);
    o.w = (u32)e[6] | ((u32)e[7] << 16);
    *(uint4*)(xb + i8) = o;
  }
}

// ---- fused GEMM + running-max + bias + relu ------------------------------
// 256^2 8-phase tail-read schedule, 3 barriers/K-step (r13: ph2-end barrier
// deleted — it certified nothing; ph3 has no ds_reads, and all WAR gaps in
// the merged [ph2+ph3] region are >= 2 barriers).  Certification chain:
//   ph1-end vmcnt(2)+BAR -> {cur A1}  certified for ph2-tail read
//   ph3-end vmcnt(2)+BAR -> {nA0,nB0} certified for ph4-tail reads
//   ph4-end vmcnt(2)+BAR -> {nB1}     certified for next ph1-tail read
__global__ __launch_bounds__(512, 1)
void gemm_max_kernel(const u16* __restrict__ xb, const u16* __restrict__ wb,
                     const float* __restrict__ b2v, const float* __restrict__ b3v,
                     const float* __restrict__ b4v, float* __restrict__ out) {
  // LPT remap: ids 0..383 -> g=2, 384..767 -> g=1, 768..1151 -> g=0
  const int id    = blockIdx.x;
  const int g     = 2 - (id / 384);
  const int id2   = id % 384;
  const int b     = id2 / 24;      // 0..15
  const int chblk = id2 % 24;      // 0..23
  const int Kp    = (g + 2) * CINP;                 // 640 / 960 / 1280
  const int nks   = Kp >> 6;                        // 10 / 15 / 20
  const int woff  = (g == 0) ? 0 : (g == 1) ? NCHP*640 : NCHP*(640+960);
  const int Lt    = LL - (g + 2) + 1;

  __shared__ __align__(16) u16 smem[4 * 16384];     // 128 KiB
  u16* A0s = smem;
  u16* B0s = smem + 16384;
  u16* A1s = smem + 32768;
  u16* B1s = smem + 49152;

  const int tid  = threadIdx.x;
  const int lane = tid & 63;
  const int w    = tid >> 6;       // 0..7
  const int wr   = w >> 2;         // 0..1 : M interleave
  const int wc   = w & 3;          // 0..3 : N interleave

  const u16* __restrict__ xrow = xb + (size_t)b * XPBP;
  const u16* __restrict__ Wg   = wb + (size_t)woff + (size_t)chblk * BN * Kp;

  // stage one 128x64 half: linear LDS dest (wave-uniform base), inverse-swizzled src
  auto STAGE = [&](const u16* src, int stride, u16* buf, int half) {
    #pragma unroll
    for (int i = 0; i < 2; i++) {
      int c = i * 512 + w * 64 + lane;                  // chunk 0..1023
      int row128 = c >> 3;
      int colb = ((c & 7) * 16) ^ ((row128 & 7) << 4);  // inverse swizzle (involution)
      gload_lds16(src + (size_t)(half * 128 + row128) * stride + (colb >> 1),
                  buf + half * 8192 + i * 4096 + w * 512);
    }
  };

  // swizzled fragment read: group grp (16 rows), ksub k
  auto FR = [&](const u16* buf, int grp, int k) -> bf16x8 {
    int row  = grp * 16 + (lane & 15);
    int colb = (k * 64 + ((lane >> 4) << 4)) ^ ((lane & 7) << 4);  // row&7 == lane&7
    return *(const bf16x8*)(buf + row * 64 + (colb >> 1));
  };

  f32x4 acc[8][4];
  #pragma unroll
  for (int mi = 0; mi < 8; mi++)
    #pragma unroll
    for (int ni = 0; ni < 4; ni++)
      acc[mi][ni] = (f32x4){0.f, 0.f, 0.f, 0.f};

  bf16x8 afrA[4][2];      // A-half-0 frags (used ph1, ph2)
  bf16x8 afrB[4][2];      // A-half-1 frags (used ph3, ph4)
  bf16x8 bfr[2][2][2];    // [nh][b2][k2]
  float rmax[4] = { -1e30f, -1e30f, -1e30f, -1e30f };

  auto FOLD = [&](int ttf) {
    #pragma unroll
    for (int mi = 0; mi < 8; mi++) {
      int tb = ttf * 256 + (mi * 2 + wr) * 16 + ((lane >> 4) << 2);
      #pragma unroll
      for (int r = 0; r < 4; r++) {
        bool ok = (tb + r) < Lt;
        #pragma unroll
        for (int ni = 0; ni < 4; ni++)
          if (ok) rmax[ni] = fmaxf(rmax[ni], acc[mi][ni][r]);
      }
      #pragma unroll
      for (int ni = 0; ni < 4; ni++)
        acc[mi][ni] = (f32x4){0.f, 0.f, 0.f, 0.f};
    }
  };

#define READ_A(DST, BUF, MH) do {                                             \
    _Pragma("unroll")                                                         \
    for (int a2 = 0; a2 < 4; a2++) {                                          \
      _Pragma("unroll")                                                       \
      for (int k2 = 0; k2 < 2; k2++)                                          \
        DST[a2][k2] = FR(BUF, ((MH)*4 + a2) * 2 + wr, k2);                    \
    }                                                                         \
  } while (0)

#define READ_B(NH, BUF) do {                                                  \
    _Pragma("unroll")                                                         \
    for (int b2 = 0; b2 < 2; b2++) {                                          \
      _Pragma("unroll")                                                       \
      for (int k2 = 0; k2 < 2; k2++)                                          \
        bfr[NH][b2][k2] = FR(BUF, ((NH)*2 + b2) * 4 + wc, k2);                \
    }                                                                         \
  } while (0)

#define MFMAQ(MH, NH, A) do {                                                 \
    __builtin_amdgcn_s_setprio(1);                                            \
    _Pragma("unroll")                                                         \
    for (int a2 = 0; a2 < 4; a2++)                                            \
      _Pragma("unroll")                                                       \
      for (int b2 = 0; b2 < 2; b2++)                                          \
        _Pragma("unroll")                                                     \
        for (int k2 = 0; k2 < 2; k2++)                                        \
          acc[(MH)*4 + a2][(NH)*2 + b2] =                                     \
            __builtin_amdgcn_mfma_f32_16x16x32_bf16(A[a2][k2],                \
              bfr[NH][b2][k2], acc[(MH)*4 + a2][(NH)*2 + b2], 0, 0, 0);       \
    __builtin_amdgcn_s_setprio(0);                                            \
  } while (0)

  const int NT = 4 * nks;    // 40 / 60 / 80 (always even)
  int tt = 0, ks = 0;

  // ---- prologue: tile0 -> buf0, order [A-h0, B-h0, B-h1, A-h1] ----
  STAGE(xrow, CINP, A0s, 0);
  STAGE(Wg,   Kp,   B0s, 0);
  STAGE(Wg,   Kp,   B0s, 1);
  STAGE(xrow, CINP, A0s, 1);
  VM2;                       // A-h0, B-h0, B-h1 certified (A-h1 outstanding)
  BAR();
  READ_A(afrA, A0s, 0);
  READ_B(0, B0s);

  // ---- steady K-loop (tiles 0 .. NT-2), 3 barriers/step ----
  for (int s = 0; s < NT - 1; s++) {
    int ks2 = ks + 1, tt2 = tt;
    if (ks2 == nks) { ks2 = 0; tt2++; }
    const u16* sA = xrow + (size_t)tt2 * (256 * CINP) + ks2 * 64;
    const u16* sB = Wg + ks2 * 64;
    u16* cA = (s & 1) ? A1s : A0s;
    u16* cB = (s & 1) ? B1s : B0s;
    u16* nA = (s & 1) ? A0s : A1s;
    u16* nB = (s & 1) ? B0s : B1s;

    // ph1
    STAGE(sA, CINP, nA, 0);
    MFMAQ(0, 0, afrA);
    READ_B(1, cB);           // cur B-h1 (certified at prev ph4-end)
    VM2;                     // certify cur A-h1 (for ph2 read)
    BAR();
    // ph2 + ph3 merged (ph2-end barrier deleted: certified reads unchanged,
    // WAR gaps >= 2 barriers, per-wave DMA chunks disjoint)
    STAGE(sB, Kp, nB, 0);
    MFMAQ(0, 1, afrA);
    READ_A(afrB, cA, 1);     // cur A-h1 (certified at ph1-end)
    STAGE(sB, Kp, nB, 1);
    MFMAQ(1, 0, afrB);
    VM2;                     // certify nA-h0, nB-h0 (for ph4 reads)
    BAR();
    // ph4
    STAGE(sA, CINP, nA, 1);
    MFMAQ(1, 1, afrB);
    READ_A(afrA, nA, 0);     // next A-h0 (certified at ph3-end)
    READ_B(0, nB);           // next B-h0 (certified at ph3-end)
    VM2;                     // certify nB-h1 (for next ph1 read)
    BAR();

    if (++ks == nks) { FOLD(tt); ks = 0; tt++; }
  }

  // ---- peeled last tile (reads buf1; no staging; drain to 0) ----
  {
    MFMAQ(0, 0, afrA);
    READ_B(1, B1s);          // certified at last steady ph4-end
    VM0;                     // certify A1s (last outstanding stage)
    BAR();
    MFMAQ(0, 1, afrA);
    READ_A(afrB, A1s, 1);    // A-h1 (certified at VM0 + BAR)
    MFMAQ(1, 0, afrB);
    MFMAQ(1, 1, afrB);
    FOLD(tt);
  }
#undef READ_A
#undef READ_B
#undef MFMAQ

  // ---- epilogue: intra-wave max, cross-wave (wr pair) combine, bias+relu ----
  float cv[4];
  #pragma unroll
  for (int ni = 0; ni < 4; ni++) {
    float v = rmax[ni];
    v = fmaxf(v, __shfl_xor(v, 16));
    v = fmaxf(v, __shfl_xor(v, 32));
    cv[ni] = v;
  }
  __syncthreads();                    // full drain; smem reusable
  float* red = (float*)smem;          // 512 floats: [wr][gn*16 + col]
  if (lane < 16) {
    #pragma unroll
    for (int ni = 0; ni < 4; ni++)
      red[wr * 256 + (ni * 4 + wc) * 16 + lane] = cv[ni];
  }
  __syncthreads();
  const float* bias = (g == 0) ? b2v : (g == 1) ? b3v : b4v;
  if (tid < 256) {
    float v = fmaxf(red[tid], red[256 + tid]);
    int ch = chblk * BN + tid;
    if (ch < NCH) {
      int n = ch / ODIM, o = ch - n * ODIM;
      out[b * (ODIM * 180) + o * 180 + g * 60 + n] = fmaxf(v + bias[ch], 0.f);
    }
  }
}

extern "C" void kernel_launch(void* const* d_in, const int* in_sizes, int n_in,
                              void* d_out, int out_size, void* d_ws, size_t ws_size,
                              hipStream_t stream) {
  const float* x  = (const float*)d_in[0];
  const float* W2 = (const float*)d_in[1];
  const float* b2 = (const float*)d_in[2];
  const float* W3 = (const float*)d_in[3];
  const float* b3 = (const float*)d_in[4];
  const float* W4 = (const float*)d_in[5];
  const float* b4 = (const float*)d_in[6];
  float* out = (float*)d_out;

  u16* xb = (u16*)d_ws;            // XELP bf16 (10.5 MB)
  u16* wb = xb + XELP;             // NCHP*(640+960+1280) bf16 (35.4 MB)

  prep_kernel<<<3 * NCHP + XELP / (256 * 8), 256, 0, stream>>>(x, W2, W3, W4, xb, wb);
  gemm_max_kernel<<<dim3(1152), 512, 0, stream>>>(xb, wb, b2, b3, b4, out);
}